// Round 14
// baseline (109.537 us; speedup 1.0000x reference)
//
#include <hip/hip_runtime.h>
#include <stdint.h>

#define D_DIM 128
#define NROW 8192          // 2B
#define L2EPS 1e-12f
// MFMA output = sim * 10/ln2 (exp2 arg): data pre-scaled by sqrt((10/ln2)/16),
// MX scales A=2^4 (131), B=2^0 (127).
#define SCALE_PRE 0.9495707f
#define LN2 0.6931471805599453f
// part slots: 0..16 row credits (by mb); 17..144 col credits (mb<16:
// 17+mb*8+wave*2+band); 145..148 diag col credits (145+wave).
#define NPART 149

typedef __attribute__((ext_vector_type(4))) int   i32x4;
typedef __attribute__((ext_vector_type(8))) int   i32x8;
typedef __attribute__((ext_vector_type(4))) float f32x4;

#define AS1 __attribute__((address_space(1)))
#define AS3 __attribute__((address_space(3)))

static __device__ inline void gload_lds16(const void* g, void* l) {
    __builtin_amdgcn_global_load_lds((const AS1 uint32_t*)g, (AS3 uint32_t*)l, 16, 0, 0);
}

static __device__ __forceinline__ void memfence_barrier() {
    asm volatile("" ::: "memory");
    __builtin_amdgcn_s_barrier();
    asm volatile("" ::: "memory");
}

static __device__ inline i32x8 cat8(i32x4 lo, i32x4 hi) {
    i32x8 r;
    r[0] = lo[0]; r[1] = lo[1]; r[2] = lo[2]; r[3] = lo[3];
    r[4] = hi[0]; r[5] = hi[1]; r[6] = hi[2]; r[7] = hi[3];
    return r;
}

// K1: L2-normalize rows of [x_i; x_j]; emit ONE fp8 e4m3 array z8 = fp8(z *
// SCALE_PRE) shared by A and B operands (MX scales reconstruct 10/ln2).
__global__ __launch_bounds__(256) void k_normalize(
        const float* __restrict__ xi, const float* __restrict__ xj,
        uint8_t* __restrict__ z8, float* __restrict__ pos_acc,
        float* __restrict__ logsum, unsigned* __restrict__ done_ct) {
    const int wave = threadIdx.x >> 6;
    const int lane = threadIdx.x & 63;
    const int row = blockIdx.x * 4 + wave;
    const float* src = (row < 4096) ? (xi + (size_t)row * D_DIM)
                                    : (xj + (size_t)(row - 4096) * D_DIM);
    float2 v = *(const float2*)(src + lane * 2);
    float ss = v.x * v.x + v.y * v.y;
#pragma unroll
    for (int m = 32; m >= 1; m >>= 1) ss += __shfl_xor(ss, m, 64);
    const float scale = SCALE_PRE / fmaxf(sqrtf(ss), L2EPS);
    const int pk = __builtin_amdgcn_cvt_pk_fp8_f32(v.x * scale, v.y * scale, 0, false);
    *(ushort*)(z8 + (size_t)row * D_DIM + lane * 2) = (ushort)pk;

    if (blockIdx.x == 0 && threadIdx.x == 0) {
        pos_acc[0] = 0.0f; logsum[0] = 0.0f; done_ct[0] = 0u;
    }
}

// Stage one 128x256 B tile (two col bands) for tile index mb, XOR-swizzled.
// 8 vmcnt units per thread. mb==16 (diag): both halves stage band rb
// (second half unused junk, kept for uniform vmcnt accounting).
static __device__ __forceinline__ void stage_tile(
        const uint8_t* __restrict__ z8, uint8_t* dst, int mb, int rb, int t) {
    const int c1 = (mb == 16) ? rb : (rb + 2 * mb + 1) & 63;
    const int c2 = (mb == 16) ? rb : (rb + 2 * mb + 2) & 63;
    const uint8_t* zb1 = z8 + (size_t)c1 * 128 * D_DIM;
    const uint8_t* zb2 = z8 + (size_t)c2 * 128 * D_DIM;
#pragma unroll
    for (int q = 0; q < 4; q++) {
        const int s = q * 256 + t;
        const int r = s >> 3;
        const int g = (s & 7) ^ (r & 7);
        gload_lds16(zb1 + (size_t)r * D_DIM + g * 16, dst + s * 16);
    }
#pragma unroll
    for (int q = 0; q < 4; q++) {
        const int s = q * 256 + t;
        const int r = s >> 3;
        const int g = (s & 7) ^ (r & 7);
        gload_lds16(zb2 + (size_t)r * D_DIM + g * 16, dst + 16384 + s * 16);
    }
}

// Compute one tile (mb, rb) from an LDS buffer; write row credits (slot mb),
// per-wave col credits (slots 17+mb*8+wave*2+band, diag 145+wave), positives
// (mb==15). r13-verified math: full credit mb<15; mb==15 j8-15 = distance-32
// (e*=0.5, sub-diag = positives); mb==16 strictly-upper diag.
static __device__ __forceinline__ void compute_tile(
        const uint8_t* __restrict__ buf, int mb, int rb,
        int wave, int lane, int quad, int lc, const i32x8* afr,
        float* __restrict__ part, float* __restrict__ pos_acc) {
    const bool diag = (mb == 16);
    const int c1 = diag ? rb : (rb + 2 * mb + 1) & 63;
    const int c2 = (rb + 2 * mb + 2) & 63;
    const int rowbase = rb * 128;
    const int rl0 = wave * 32 + quad * 4;

    float rs[2][4] = {{0.f,0.f,0.f,0.f},{0.f,0.f,0.f,0.f}};
    float cs[16];
#pragma unroll
    for (int j = 0; j < 16; j++) cs[j] = 0.f;
    float posp = 0.f;

#define MFMA_J(j, A0, A1)                                                     \
    i32x4 blo, bhi; {                                                         \
        const int rowb = ((j) * 16 + lc) * D_DIM;                             \
        blo = *(const i32x4*)&buf[rowb + (((quad * 2)     ^ (lc & 7)) * 16)]; \
        bhi = *(const i32x4*)&buf[rowb + (((quad * 2 + 1) ^ (lc & 7)) * 16)]; \
    }                                                                         \
    const i32x8 bfr = cat8(blo, bhi);                                         \
    f32x4 z4 = {0.f, 0.f, 0.f, 0.f};                                          \
    f32x4 A0 = __builtin_amdgcn_mfma_scale_f32_16x16x128_f8f6f4(              \
                   afr[0], bfr, z4, 0, 0, 0, 131, 0, 127);                    \
    f32x4 A1 = __builtin_amdgcn_mfma_scale_f32_16x16x128_f8f6f4(              \
                   afr[1], bfr, z4, 0, 0, 0, 131, 0, 127);

    if (!diag) {
#pragma unroll
        for (int j = 0; j < 8; j++) {        // band c1: always full credit
            MFMA_J(j, a0, a1)
#pragma unroll
            for (int r = 0; r < 4; r++) {
                const float e0 = exp2f(a0[r]);
                const float e1 = exp2f(a1[r]);
                rs[0][r] += e0;
                rs[1][r] += e1;
                cs[j] += e0 + e1;
            }
        }
        if (mb < 15) {                        // band c2: full credit
#pragma unroll
            for (int j = 8; j < 16; j++) {
                MFMA_J(j, a0, a1)
#pragma unroll
                for (int r = 0; r < 4; r++) {
                    const float e0 = exp2f(a0[r]);
                    const float e1 = exp2f(a1[r]);
                    rs[0][r] += e0;
                    rs[1][r] += e1;
                    cs[j] += e0 + e1;
                }
            }
        } else {                              // distance-32: halve; diag = positives
#pragma unroll
            for (int j = 8; j < 16; j++) {
                MFMA_J(j, a0, a1)
                const int clb = (j - 8) * 16 + lc;
#pragma unroll
                for (int i = 0; i < 2; i++)
#pragma unroll
                    for (int r = 0; r < 4; r++) {
                        const float s = (i ? a1 : a0)[r];
                        const float e = 0.5f * exp2f(s);
                        if (clb == rl0 + i * 16 + r) posp += s;
                        rs[i][r] += e;
                        cs[j] += e;
                    }
            }
        }
    } else {                                  // diagonal tile: strictly upper
#pragma unroll
        for (int j = 0; j < 8; j++) {
            MFMA_J(j, a0, a1)
            const int cl = j * 16 + lc;
#pragma unroll
            for (int i = 0; i < 2; i++)
#pragma unroll
                for (int r = 0; r < 4; r++) {
                    const float s = (i ? a1 : a0)[r];
                    const float e = (cl > rl0 + i * 16 + r) ? exp2f(s) : 0.f;
                    rs[i][r] += e;
                    cs[j] += e;
                }
        }
    }
#undef MFMA_J

    // Row credits -> slot mb (reduce over the 16 col-lanes).
#pragma unroll
    for (int i = 0; i < 2; i++)
#pragma unroll
        for (int r = 0; r < 4; r++) {
            float v = rs[i][r];
            v += __shfl_xor(v, 1, 64);
            v += __shfl_xor(v, 2, 64);
            v += __shfl_xor(v, 4, 64);
            v += __shfl_xor(v, 8, 64);
            if (lc == 0)
                part[(size_t)mb * NROW + rowbase + rl0 + i * 16 + r] = v;
        }

    // Col credits: quad-reduce; per-wave single-writer slots (no LDS needed).
    const int njc = diag ? 8 : 16;
    for (int j = 0; j < njc; j++) {
        cs[j] += __shfl_xor(cs[j], 16, 64);
        cs[j] += __shfl_xor(cs[j], 32, 64);
    }
    if (quad == 0) {
        if (!diag) {
#pragma unroll
            for (int j = 0; j < 8; j++)
                part[(size_t)(17 + mb * 8 + wave * 2) * NROW + c1 * 128 + j * 16 + lc] = cs[j];
#pragma unroll
            for (int j = 8; j < 16; j++)
                part[(size_t)(17 + mb * 8 + wave * 2 + 1) * NROW + c2 * 128 + (j - 8) * 16 + lc] = cs[j];
        } else {
#pragma unroll
            for (int j = 0; j < 8; j++)
                part[(size_t)(145 + wave) * NROW + c1 * 128 + j * 16 + lc] = cs[j];
        }
    }

    if (mb == 15) {
#pragma unroll
        for (int mm = 32; mm >= 1; mm >>= 1) posp += __shfl_xor(posp, mm, 64);
        if (lane == 0) atomicAdd(pos_acc, posp);
    }
}

// K2 (persistent pipeline): 512 blocks (2/CU, one generation). Block b owns
// tiles (mb0, rb), (mb0+8, rb) [, (16, rb) if b<64] -- same rb, so A-frags
// load once. B tiles stream through a 2x32KB LDS double-buffer, prefetched
// one tile ahead; raw s_barrier + manual s_waitcnt vmcnt(8) keeps the next
// tile's DMA in flight under the current tile's compute (no __syncthreads,
// no vmcnt(0) drain mid-pipeline).
__global__ __launch_bounds__(256) void k_gemm(
        const uint8_t* __restrict__ z8, float* __restrict__ part,
        float* __restrict__ pos_acc) {
    __shared__ __align__(16) uint8_t lds[2][32768];   // 64 KB -> 2 blocks/CU

    const int t = threadIdx.x;
    const int wave = t >> 6, lane = t & 63;
    const int quad = lane >> 4, lc = lane & 15;

    const int b = blockIdx.x;           // 0..511
    const int rb = b & 63;
    const int mb0 = b >> 6;             // 0..7
    const int nt = (b < 64) ? 3 : 2;    // third tile = diag (half work)
    const int rowbase = rb * 128;

    // A fragments, direct global loads (issued before the DMAs; compiler
    // guards their first use with its own precise vmcnt).
    i32x8 afr[2];
    {
        const uint8_t* pa = z8 + (size_t)(rowbase + wave * 32 + lc) * D_DIM + quad * 32;
#pragma unroll
        for (int i = 0; i < 2; i++) {
            i32x4 lo = *(const i32x4*)(pa + i * 16 * D_DIM);
            i32x4 hi = *(const i32x4*)(pa + i * 16 * D_DIM + 16);
            afr[i] = cat8(lo, hi);
        }
    }

    // Prologue: stage tile0 and tile1 (8 vm units each).
    stage_tile(z8, lds[0], mb0, rb, t);
    stage_tile(z8, lds[1], mb0 + 8, rb, t);
    asm volatile("s_waitcnt vmcnt(8)" ::: "memory");   // tile0 (+A) done
    memfence_barrier();

    for (int tt = 0; tt < nt; tt++) {
        const int mb = (tt == 2) ? 16 : mb0 + 8 * tt;
        compute_tile(lds[tt & 1], mb, rb, wave, lane, quad, lc, afr,
                     part, pos_acc);
        if (tt + 2 < nt) {              // re-stage current buffer for tile tt+2
            memfence_barrier();         // all waves done reading lds[tt&1]
            stage_tile(z8, lds[tt & 1], 16, rb, t);
        }
        if (tt + 1 < nt) {              // wait own DMA for tile tt+1, then sync
            if (tt + 2 < nt)
                asm volatile("s_waitcnt vmcnt(8)" ::: "memory");
            else
                asm volatile("s_waitcnt vmcnt(0)" ::: "memory");
            memfence_barrier();
        }
    }
}

// K3 (fused logsum + combine): 32 blocks, one row per thread; last block
// (atomic counter) writes the final loss. pos_acc holds scaled sim over both
// appearances of each positive pair -> factor ln2.
__global__ __launch_bounds__(256) void k_logsum(
        const float* __restrict__ part, float* __restrict__ pos_acc,
        float* __restrict__ logsum, unsigned* __restrict__ done_ct,
        float* __restrict__ out) {
    const int row = blockIdx.x * 256 + threadIdx.x;
    float d = 0.f;
    for (int p = 0; p < NPART; p++) d += part[(size_t)p * NROW + row];
    float v = __logf(d);
#pragma unroll
    for (int m = 32; m >= 1; m >>= 1) v += __shfl_xor(v, m, 64);
    if ((threadIdx.x & 63) == 0) atomicAdd(logsum, v);
    __threadfence();
    __syncthreads();
    if (threadIdx.x == 0) {
        const unsigned prev = atomicAdd(done_ct, 1u);
        if (prev == gridDim.x - 1) {
            __threadfence();
            const float ls = atomicAdd(logsum, 0.0f);
            const float pp = atomicAdd(pos_acc, 0.0f);
            out[0] = (ls - pp * LN2) / (float)NROW;
        }
    }
}

extern "C" void kernel_launch(void* const* d_in, const int* in_sizes, int n_in,
                              void* d_out, int out_size, void* d_ws, size_t ws_size,
                              hipStream_t stream) {
    const float* xi = (const float*)d_in[0];
    const float* xj = (const float*)d_in[1];
    uint8_t* z8 = (uint8_t*)d_ws;                                // 1 MB fp8
    float* part = (float*)(z8 + (size_t)NROW * D_DIM);           // 149 x 8192 f32
    float* pos_acc = part + (size_t)NPART * NROW;
    float* logsum = pos_acc + 1;
    unsigned* done_ct = (unsigned*)(logsum + 1);
    float* out = (float*)d_out;

    hipLaunchKernelGGL(k_normalize, dim3(NROW / 4), dim3(256), 0, stream,
                       xi, xj, z8, pos_acc, logsum, done_ct);
    hipLaunchKernelGGL(k_gemm, dim3(512), dim3(256), 0, stream,
                       z8, part, pos_acc);
    hipLaunchKernelGGL(k_logsum, dim3(NROW / 256), dim3(256), 0, stream,
                       part, pos_acc, logsum, done_ct, out);
}

// Round 15
// 80.731 us; speedup vs baseline: 1.3568x; 1.3568x over previous
//
#include <hip/hip_runtime.h>
#include <stdint.h>

#define D_DIM 128
#define NROW 8192          // 2B
#define L2EPS 1e-12f
// MFMA output = sim * 10/ln2 (exp2 arg): data pre-scaled by sqrt((10/ln2)/16),
// MX scales A=2^4 (131), B=2^0 (127).
#define SCALE_PRE 0.9495707f
#define LN2 0.6931471805599453f
#define NPART 50           // row slots 0..16 (mb), col slots 17..48, diag col 49

typedef __attribute__((ext_vector_type(4))) int   i32x4;
typedef __attribute__((ext_vector_type(8))) int   i32x8;
typedef __attribute__((ext_vector_type(4))) float f32x4;

#define AS1 __attribute__((address_space(1)))
#define AS3 __attribute__((address_space(3)))

static __device__ inline void gload_lds16(const void* g, void* l) {
    __builtin_amdgcn_global_load_lds((const AS1 uint32_t*)g, (AS3 uint32_t*)l, 16, 0, 0);
}

static __device__ inline i32x8 cat8(i32x4 lo, i32x4 hi) {
    i32x8 r;
    r[0] = lo[0]; r[1] = lo[1]; r[2] = lo[2]; r[3] = lo[3];
    r[4] = hi[0]; r[5] = hi[1]; r[6] = hi[2]; r[7] = hi[3];
    return r;
}

// Native 2^x: our arguments are |x| <= ~15 (sim*10/ln2), far from the
// denormal/overflow edges the OCML exp2f wrapper guards -> raw v_exp_f32.
static __device__ __forceinline__ float fexp2(float x) {
#if __has_builtin(__builtin_amdgcn_exp2f)
    return __builtin_amdgcn_exp2f(x);
#else
    float r;
    asm("v_exp_f32 %0, %1" : "=v"(r) : "v"(x));
    return r;
#endif
}

// Sum over the 16-lane DPP row on the VALU pipe (no ds_bpermute / LDS pipe).
// Result valid in lane 15 of each 16-lane row.
static __device__ __forceinline__ float dpp_row_sum16(float v) {
    union { float f; int i; } u, s;
    u.f = v;
    s.i = __builtin_amdgcn_update_dpp(0, u.i, 0x118, 0xF, 0xF, true); u.f += s.f; // row_shr:8
    s.i = __builtin_amdgcn_update_dpp(0, u.i, 0x114, 0xF, 0xF, true); u.f += s.f; // row_shr:4
    s.i = __builtin_amdgcn_update_dpp(0, u.i, 0x112, 0xF, 0xF, true); u.f += s.f; // row_shr:2
    s.i = __builtin_amdgcn_update_dpp(0, u.i, 0x111, 0xF, 0xF, true); u.f += s.f; // row_shr:1
    return u.f;
}

// K1: L2-normalize rows of [x_i; x_j]; emit ONE fp8 e4m3 array
// z8 = fp8(z * SCALE_PRE), shared by A and B operands (MX scales 2^4 / 2^0
// reconstruct the 10/ln2 factor in the MFMA output).
__global__ __launch_bounds__(256) void k_normalize(
        const float* __restrict__ xi, const float* __restrict__ xj,
        uint8_t* __restrict__ z8, float* __restrict__ pos_acc,
        float* __restrict__ logsum, unsigned* __restrict__ done_ct) {
    const int wave = threadIdx.x >> 6;
    const int lane = threadIdx.x & 63;
    const int row = blockIdx.x * 4 + wave;
    const float* src = (row < 4096) ? (xi + (size_t)row * D_DIM)
                                    : (xj + (size_t)(row - 4096) * D_DIM);
    float2 v = *(const float2*)(src + lane * 2);
    float ss = v.x * v.x + v.y * v.y;
#pragma unroll
    for (int m = 32; m >= 1; m >>= 1) ss += __shfl_xor(ss, m, 64);
    const float scale = SCALE_PRE / fmaxf(sqrtf(ss), L2EPS);
    const int pk = __builtin_amdgcn_cvt_pk_fp8_f32(v.x * scale, v.y * scale, 0, false);
    *(ushort*)(z8 + (size_t)row * D_DIM + lane * 2) = (ushort)pk;

    if (blockIdx.x == 0 && threadIdx.x == 0) {
        pos_acc[0] = 0.0f; logsum[0] = 0.0f; done_ct[0] = 0u;
    }
}

// K2 (paired-circulant symmetric): block (mb=bid>>6 in 0..16, rb=bid&63).
//  mb<16 : rows band rb x col bands c1=(rb+2mb+1)%64, c2=(rb+2mb+2)%64
//          (128x256 tile). Distances 1..31 covered once (full credit);
//          mb==15's second half = distance 32, double-enumerated -> e*=0.5,
//          sub-tile diagonal = positive pairs (both directions accumulated).
//  mb==16: diagonal tile rb x rb, strictly-upper (c>r) only.
// Each e credits denom[row] (slot mb) and denom[col] (slots 17+2mb / +1;
// diag col slot 49). All 50 slots single-writer & fully covered -> no atomics,
// no zeroing. B bands LDS-resident (XOR swizzle) after ONE barrier.
// MFMA: mfma_scale_f32_16x16x128_f8f6f4, scale_a=131 (x16), scale_b=127 (x1).
__global__ __launch_bounds__(256) void k_gemm(
        const uint8_t* __restrict__ z8, float* __restrict__ part,
        float* __restrict__ pos_acc) {
    __shared__ __align__(16) uint8_t lds[32768];   // 256 B-rows x 128 B fp8

    const int t = threadIdx.x;
    const int wave = t >> 6, lane = t & 63;
    const int quad = lane >> 4, lc = lane & 15;

    const int mb = blockIdx.x >> 6;     // 0..16
    const int rb = blockIdx.x & 63;
    const int rowbase = rb * 128;
    const bool diag = (mb == 16);
    const int c1 = diag ? rb : (rb + 2 * mb + 1) & 63;
    const int c2 = (rb + 2 * mb + 2) & 63;          // unused when diag

    // Stage B: band c1 -> lds rows 0..127, band c2 -> rows 128..255.
    // Slot s: row r=s>>3, slot-unit u holds global 16B-unit u^(r&7).
    {
        const uint8_t* zb1 = z8 + (size_t)c1 * 128 * D_DIM;
#pragma unroll
        for (int q = 0; q < 4; q++) {
            const int s = q * 256 + t;
            const int r = s >> 3;
            const int g = (s & 7) ^ (r & 7);
            gload_lds16(zb1 + (size_t)r * D_DIM + g * 16, &lds[s * 16]);
        }
        if (!diag) {
            const uint8_t* zb2 = z8 + (size_t)c2 * 128 * D_DIM;
#pragma unroll
            for (int q = 0; q < 4; q++) {
                const int s = q * 256 + t;
                const int r = s >> 3;
                const int g = (s & 7) ^ (r & 7);
                gload_lds16(zb2 + (size_t)r * D_DIM + g * 16, &lds[16384 + s * 16]);
            }
        }
    }

    // A fragments: 32 B of row (rowbase + wave*32 + i*16 + lc), bytes [quad*32,+32).
    i32x8 afr[2];
    {
        const uint8_t* pa = z8 + (size_t)(rowbase + wave * 32 + lc) * D_DIM + quad * 32;
#pragma unroll
        for (int i = 0; i < 2; i++) {
            i32x4 lo = *(const i32x4*)(pa + i * 16 * D_DIM);
            i32x4 hi = *(const i32x4*)(pa + i * 16 * D_DIM + 16);
            afr[i] = cat8(lo, hi);
        }
    }

    asm volatile("s_waitcnt vmcnt(0)" ::: "memory");
    __syncthreads();   // B resident; j-loops below are barrier-free

    float rs[2][4] = {{0.f,0.f,0.f,0.f},{0.f,0.f,0.f,0.f}};
    float cs[16];
#pragma unroll
    for (int j = 0; j < 16; j++) cs[j] = 0.f;
    float posp = 0.f;
    const int rl0 = wave * 32 + quad * 4;   // local row = rl0 + i*16 + r

    // B-row jr = j*16+lc; jr&7 == lc&7, so read slot-units (quad*2..+1)^(lc&7).
#define MFMA_J(j, A0, A1)                                                     \
    i32x4 blo, bhi; {                                                         \
        const int rowb = ((j) * 16 + lc) * D_DIM;                             \
        blo = *(const i32x4*)&lds[rowb + (((quad * 2)     ^ (lc & 7)) * 16)]; \
        bhi = *(const i32x4*)&lds[rowb + (((quad * 2 + 1) ^ (lc & 7)) * 16)]; \
    }                                                                         \
    const i32x8 bfr = cat8(blo, bhi);                                         \
    f32x4 z4 = {0.f, 0.f, 0.f, 0.f};                                          \
    f32x4 A0 = __builtin_amdgcn_mfma_scale_f32_16x16x128_f8f6f4(              \
                   afr[0], bfr, z4, 0, 0, 0, 131, 0, 127);                    \
    f32x4 A1 = __builtin_amdgcn_mfma_scale_f32_16x16x128_f8f6f4(              \
                   afr[1], bfr, z4, 0, 0, 0, 131, 0, 127);

    if (!diag) {
#pragma unroll
        for (int j = 0; j < 8; j++) {        // band c1: always full credit
            MFMA_J(j, a0, a1)
#pragma unroll
            for (int r = 0; r < 4; r++) {
                const float e0 = fexp2(a0[r]);
                const float e1 = fexp2(a1[r]);
                rs[0][r] += e0;
                rs[1][r] += e1;
                cs[j] += e0 + e1;
            }
        }
        if (mb < 15) {                        // band c2: full credit
#pragma unroll
            for (int j = 8; j < 16; j++) {
                MFMA_J(j, a0, a1)
#pragma unroll
                for (int r = 0; r < 4; r++) {
                    const float e0 = fexp2(a0[r]);
                    const float e1 = fexp2(a1[r]);
                    rs[0][r] += e0;
                    rs[1][r] += e1;
                    cs[j] += e0 + e1;
                }
            }
        } else {                              // distance-32: halve; diag = positives
#pragma unroll
            for (int j = 8; j < 16; j++) {
                MFMA_J(j, a0, a1)
                const int clb = (j - 8) * 16 + lc;   // band-local col
#pragma unroll
                for (int i = 0; i < 2; i++)
#pragma unroll
                    for (int r = 0; r < 4; r++) {
                        const float s = (i ? a1 : a0)[r];
                        const float e = 0.5f * fexp2(s);
                        if (clb == rl0 + i * 16 + r) posp += s;
                        rs[i][r] += e;
                        cs[j] += e;
                    }
            }
        }
    } else {                                  // diagonal tile: strictly upper
#pragma unroll
        for (int j = 0; j < 8; j++) {
            MFMA_J(j, a0, a1)
            const int cl = j * 16 + lc;
#pragma unroll
            for (int i = 0; i < 2; i++)
#pragma unroll
                for (int r = 0; r < 4; r++) {
                    const float s = (i ? a1 : a0)[r];
                    const float e = (cl > rl0 + i * 16 + r) ? fexp2(s) : 0.f;
                    rs[i][r] += e;
                    cs[j] += e;
                }
        }
    }
#undef MFMA_J

    // Row credits -> slot mb: DPP row-sum over the 16 col-lanes (VALU pipe;
    // result lands in lane 15 of each DPP row).
#pragma unroll
    for (int i = 0; i < 2; i++)
#pragma unroll
        for (int r = 0; r < 4; r++) {
            const float v = dpp_row_sum16(rs[i][r]);
            if (lc == 15)
                part[(size_t)mb * NROW + rowbase + rl0 + i * 16 + r] = v;
        }

    // Col credits: quad-reduce (cross-row -> bpermute), cross-wave LDS reduce.
#pragma unroll
    for (int j = 0; j < 16; j++) {
        cs[j] += __shfl_xor(cs[j], 16, 64);
        cs[j] += __shfl_xor(cs[j], 32, 64);
    }
    __syncthreads();                    // all B reads done; reuse LDS
    float* colred = (float*)lds;        // [4][256]
    if (quad == 0) {
#pragma unroll
        for (int j = 0; j < 16; j++)
            colred[wave * 256 + j * 16 + lc] = cs[j];
    }
    __syncthreads();
    if (t < 256) {
        const float v = colred[t] + colred[256 + t] + colred[512 + t] + colred[768 + t];
        if (!diag) {
            const int slot = 17 + 2 * mb + (t >> 7);
            const int band = (t < 128) ? c1 : c2;
            part[(size_t)slot * NROW + band * 128 + (t & 127)] = v;
        } else if (t < 128) {
            part[(size_t)49 * NROW + c1 * 128 + t] = v;
        }
    }

    if (mb == 15) {
#pragma unroll
        for (int mm = 32; mm >= 1; mm >>= 1) posp += __shfl_xor(posp, mm, 64);
        if (lane == 0) atomicAdd(pos_acc, posp);
    }
}

// K3 (fused logsum + combine): 32 blocks, one row per thread; last block
// (atomic counter) writes the final loss. pos_acc holds scaled sim over both
// appearances of each positive pair -> factor ln2.
__global__ __launch_bounds__(256) void k_logsum(
        const float* __restrict__ part, float* __restrict__ pos_acc,
        float* __restrict__ logsum, unsigned* __restrict__ done_ct,
        float* __restrict__ out) {
    const int row = blockIdx.x * 256 + threadIdx.x;
    float d = 0.f;
#pragma unroll
    for (int p = 0; p < NPART; p++) d += part[(size_t)p * NROW + row];
    float v = __logf(d);
#pragma unroll
    for (int m = 32; m >= 1; m >>= 1) v += __shfl_xor(v, m, 64);
    if ((threadIdx.x & 63) == 0) atomicAdd(logsum, v);
    __threadfence();
    __syncthreads();
    if (threadIdx.x == 0) {
        const unsigned prev = atomicAdd(done_ct, 1u);
        if (prev == gridDim.x - 1) {          // last block: all adds visible
            __threadfence();
            const float ls = atomicAdd(logsum, 0.0f);
            const float pp = atomicAdd(pos_acc, 0.0f);
            out[0] = (ls - pp * LN2) / (float)NROW;
        }
    }
}

extern "C" void kernel_launch(void* const* d_in, const int* in_sizes, int n_in,
                              void* d_out, int out_size, void* d_ws, size_t ws_size,
                              hipStream_t stream) {
    const float* xi = (const float*)d_in[0];
    const float* xj = (const float*)d_in[1];
    uint8_t* z8 = (uint8_t*)d_ws;                                // 1 MB fp8
    float* part = (float*)(z8 + (size_t)NROW * D_DIM);           // 50 x 8192 f32
    float* pos_acc = part + (size_t)NPART * NROW;
    float* logsum = pos_acc + 1;
    unsigned* done_ct = (unsigned*)(logsum + 1);
    float* out = (float*)d_out;

    hipLaunchKernelGGL(k_normalize, dim3(NROW / 4), dim3(256), 0, stream,
                       xi, xj, z8, pos_acc, logsum, done_ct);
    hipLaunchKernelGGL(k_gemm, dim3(17 * 64), dim3(256), 0, stream,
                       z8, part, pos_acc);
    hipLaunchKernelGGL(k_logsum, dim3(NROW / 256), dim3(256), 0, stream,
                       part, pos_acc, logsum, done_ct, out);
}